// Round 5
// baseline (319.295 us; speedup 1.0000x reference)
//
#include <hip/hip_runtime.h>
#include <cstdint>
#include <cstddef>

// Problem constants
#define B_    2
#define S_    2048
#define HQ_   32
#define HKV_  8
#define D_    128
#define QSCALE_ (0.08838834764831845f * 1.4426950408889634f)  // fold log2(e): softmax in base 2

#define NROW_ (B_*S_*HKV_)   // 32768 rows per tensor

typedef __bf16 bf16x8 __attribute__((ext_vector_type(8)));
typedef float  f32x4  __attribute__((ext_vector_type(4)));
typedef unsigned int u32x4 __attribute__((ext_vector_type(4)));

__device__ __forceinline__ unsigned int f2bfu(float f) {
    __bf16 b = (__bf16)f;           // RTNE
    return (unsigned int)__builtin_bit_cast(unsigned short, b);
}

// async 16B/lane global->LDS; lds base must be wave-uniform (HW adds lane*16)
__device__ __forceinline__ void gl_lds16(const unsigned short* g, unsigned short* l) {
    __builtin_amdgcn_global_load_lds(
        (const __attribute__((address_space(1))) void*)g,
        (__attribute__((address_space(3))) void*)l, 16, 0, 0);
}

// Emulate reference quant_dequant_e4m3 exactly, branch/libcall-free.
__device__ __forceinline__ float qd_e4m3(float x) {
    float ax = fabsf(x);
    float xc = fminf(fmaxf(x, -448.f), 448.f);
    float axc = fmaxf(ax, 1e-12f);
    int e = (int)((__builtin_bit_cast(unsigned int, axc) >> 23) & 255u) - 127;
    e = min(max(e, -6), 8);
    float s1 = __builtin_bit_cast(float, (unsigned int)(130 - e) << 23); // 2^(3-e)
    float s2 = __builtin_bit_cast(float, (unsigned int)(124 + e) << 23); // 2^(e-3)
    float q = rintf(xc * s1) * s2;
    return ax == 0.f ? 0.f : q;
}

// fp4 e2m1 quant-dequant; searchsorted 'left' => ties at midpoints go DOWN
__device__ __forceinline__ float qd_fp4(float x, float scale) {
    float xn = x / scale;                    // IEEE div, matches numpy
    float a = fabsf(xn);
    float g;
    if      (a <= 0.25f) g = 0.f;
    else if (a <= 0.75f) g = 0.5f;
    else if (a <= 1.25f) g = 1.f;
    else if (a <= 1.75f) g = 1.5f;
    else if (a <= 2.5f)  g = 2.f;
    else if (a <= 3.5f)  g = 3.f;
    else if (a <= 5.f)   g = 4.f;
    else                 g = 6.f;
    return copysignf(g * scale, xn);
}

// Fused prep kernel (round-2/3-proven, passed).
// Blocks [0, 8192): quantize K -> bf16 dequantized [b][hkv][s][d].
// Blocks [8192, 8704): quantize V AND transpose to [b][hkv][d][s] in one pass.
__global__ __launch_bounds__(256) void prep(const float* __restrict__ k,
                                            const float* __restrict__ v,
                                            unsigned short* __restrict__ kd,
                                            unsigned short* __restrict__ vdT) {
    __shared__ alignas(16) unsigned short t[64][136];  // +8 pad (V path only)
    if (blockIdx.x < 8192) {
        // ---- K path: one wave per row, 2 elems/lane ----
        int gw = (blockIdx.x * 256 + threadIdx.x) >> 6;
        int lane = threadIdx.x & 63;
        int row = gw;
        int b   = row / (S_ * HKV_);
        int rem = row - b * (S_ * HKV_);
        int s   = rem >> 3;      // HKV = 8
        int h   = rem & 7;
        float2 x = *(const float2*)(k + (size_t)row * D_ + 2 * lane);
        float q0 = qd_e4m3(x.x);
        float q1 = qd_e4m3(x.y);
        float amax = fmaxf(fabsf(q0), fabsf(q1));
#pragma unroll
        for (int m = 1; m < 64; m <<= 1) amax = fmaxf(amax, __shfl_xor(amax, m, 64));
        float scale = fmaxf(amax / 6.0f, 1e-12f);
        float y0 = qd_fp4(q0, scale);
        float y1 = qd_fp4(q1, scale);
        size_t outOff = ((size_t)(b * HKV_ + h) * S_ + s) * D_ + 2 * lane;
        unsigned int pack = f2bfu(y0) | (f2bfu(y1) << 16);
        *(unsigned int*)(kd + outOff) = pack;
    } else {
        // ---- V path: quant (rows in pairs to pipeline shuffle-reduce chains)
        // then LDS transpose ----
        int bid = blockIdx.x - 8192;     // 0..511
        int bh = bid >> 5;               // b*HKV + h, 0..15
        int st = bid & 31;
        int s0 = st * 64;
        int b = bh >> 3;
        int h = bh & 7;
        int tid = threadIdx.x;
        int lane = tid & 63;
        int wave = tid >> 6;
#pragma unroll
        for (int i = 0; i < 8; ++i) {
            int rA = wave * 16 + 2 * i;
            const float* srcA = v + (((size_t)b * S_ + (s0 + rA)) * HKV_ + h) * D_ + 2 * lane;
            const float* srcB = srcA + (size_t)HKV_ * D_;   // next s
            float2 xA = *(const float2*)srcA;
            float2 xB = *(const float2*)srcB;
            float a0 = qd_e4m3(xA.x), a1 = qd_e4m3(xA.y);
            float c0 = qd_e4m3(xB.x), c1 = qd_e4m3(xB.y);
            float amA = fmaxf(fabsf(a0), fabsf(a1));
            float amB = fmaxf(fabsf(c0), fabsf(c1));
#pragma unroll
            for (int m = 1; m < 64; m <<= 1) {   // two independent chains interleave
                amA = fmaxf(amA, __shfl_xor(amA, m, 64));
                amB = fmaxf(amB, __shfl_xor(amB, m, 64));
            }
            float sA = fmaxf(amA / 6.0f, 1e-12f);
            float sB = fmaxf(amB / 6.0f, 1e-12f);
            unsigned int pA = f2bfu(qd_fp4(a0, sA)) | (f2bfu(qd_fp4(a1, sA)) << 16);
            unsigned int pB = f2bfu(qd_fp4(c0, sB)) | (f2bfu(qd_fp4(c1, sB)) << 16);
            *(unsigned int*)&t[rA][2 * lane]     = pA;
            *(unsigned int*)&t[rA + 1][2 * lane] = pB;
        }
        __syncthreads();
        int d = tid >> 1;
        unsigned short* dp = vdT + ((size_t)bh * D_ + d) * S_ + s0;
#pragma unroll
        for (int i = 0; i < 4; ++i) {
            int c = (tid & 1) + 2 * i;
            int so = c * 8;
            unsigned short tmp[8];
#pragma unroll
            for (int e = 0; e < 8; ++e) tmp[e] = t[so + e][d];
            *(uint4*)(dp + so) = *(uint4*)tmp;
        }
    }
}

// P redistribution C-layout -> PV A-fragment, in registers (round-3-verified):
// 2x permlane32_swap + 2x permlane16_swap per 32-key chunk.
__device__ __forceinline__ bf16x8 permpack(const unsigned int* Dlo,
                                           const unsigned int* Dhi, int kc) {
    auto p0 = __builtin_amdgcn_permlane32_swap(Dlo[2 * kc], Dlo[2 * kc + 1], false, false);
    auto p1 = __builtin_amdgcn_permlane32_swap(Dhi[2 * kc], Dhi[2 * kc + 1], false, false);
    auto r0 = __builtin_amdgcn_permlane16_swap(p0[0], p0[1], false, false);
    auto r1 = __builtin_amdgcn_permlane16_swap(p1[0], p1[1], false, false);
    u32x4 pau = (u32x4){r0[0], r1[0], r0[1], r1[1]};  // A-dwords 0..3
    return __builtin_bit_cast(bf16x8, pau);
}

// Kernel 2: causal GQA flash attention.
// THEORY THIS ROUND: ds_read_b128 ~12cy vs mfma_16x16x32 ~5cy => a 1 read :
// 1 MFMA kernel is LDS-pipe-bound by construction (~94us floor, matches the
// invariant 147us across rounds 0/2/3). Fix: each wave owns TWO 16-q groups
// (128q block) so every K/V fragment read feeds TWO MFMAs -> LDS-read demand
// halves, read:MFMA ~balanced. Round 1 tried this but __syncthreads() drained
// vmcnt(0) (killing the prefetch) AND halved occupancy — never a fair test.
// Here: single-buffer 32KB LDS (no occupancy loss), P in registers (permlane,
// round-3-verified), and split RAW barriers with counted vmcnt (m201 template):
//   stage K,V -> vmcnt(4)+bar (K ready, V flying) -> QK/SM (hides V latency)
//   -> vmcnt(0)+bar -> PV -> lgkmcnt(0)+bar (safe to overwrite).
__global__ __launch_bounds__(256, 3) void attn(const float* __restrict__ q,
                                               const unsigned short* __restrict__ kd,
                                               const unsigned short* __restrict__ vdT,
                                               float* __restrict__ out) {
    int bh = blockIdx.x;           // 0..63
    int qt = 15 - blockIdx.y;      // heaviest q-tiles dispatched first
    int b  = bh >> 5;
    int hq = bh & 31;
    int hkv = hq >> 2;             // GQA group of 4
    int tid  = threadIdx.x;
    int lane = tid & 63;
    int wave = tid >> 6;
    int m16  = lane & 15;
    int g    = lane >> 4;
    int m8   = m16 & 7;

    __shared__ alignas(16) unsigned short ks[64 * 128];    // K [key][d], swz ^(key&15) on 16B
    __shared__ alignas(16) unsigned short vs[128 * 64];    // V^T [d][key], swz ^(d&7) on 16B

    const unsigned short* kbase = kd  + (size_t)(b * HKV_ + hkv) * S_ * D_;
    const unsigned short* vbase = vdT + (size_t)(b * HKV_ + hkv) * D_ * S_;

    bf16x8 vones;
#pragma unroll
    for (int j = 0; j < 8; ++j) vones[j] = (__bf16)1.0f;

    int q0 = qt * 128;
    int nkt = 2 * qt + 2;          // 64-key tiles in causal range

    // stage one 64-key tile: K first (4 loads), then V (4 loads) — issue order
    // matters for the counted vmcnt(4) below.
    auto stage = [&](int k0s) {
#pragma unroll
        for (int i = 0; i < 4; ++i) {
            int row = wave * 16 + i * 4 + (lane >> 4);
            int c = (lane & 15) ^ (row & 15);
            gl_lds16(kbase + (size_t)(k0s + row) * D_ + c * 8,
                     &ks[wave * 2048 + i * 512]);
        }
#pragma unroll
        for (int i = 0; i < 4; ++i) {
            int d = wave * 32 + i * 8 + (lane >> 3);
            int c = (lane & 7) ^ (d & 7);
            gl_lds16(vbase + (size_t)d * S_ + k0s + c * 8,
                     &vs[wave * 2048 + i * 512]);
        }
    };

    // prologue: start tile 0 staging before Q-prep (loads fly under the cvts)
    stage(0);

    // Q fragments for both 16-q groups, pre-scaled by SCALING*log2e
    bf16x8 qf0[4], qf1[4];
    {
        const float* qp0 = q + (((size_t)b * S_ + (q0 + wave * 32 + m16)) * HQ_ + hq) * D_;
        const float* qp1 = qp0 + (size_t)16 * HQ_ * D_;
#pragma unroll
        for (int c = 0; c < 4; ++c) {
            const float* a0 = qp0 + c * 32 + g * 8;
            const float* a1 = qp1 + c * 32 + g * 8;
            bf16x8 f0, f1;
#pragma unroll
            for (int j = 0; j < 8; ++j) {
                f0[j] = (__bf16)(a0[j] * QSCALE_);
                f1[j] = (__bf16)(a1[j] * QSCALE_);
            }
            qf0[c] = f0;
            qf1[c] = f1;
        }
    }

    f32x4 o0[8], o1[8];
#pragma unroll
    for (int i = 0; i < 8; ++i) { o0[i] = (f32x4){0.f,0.f,0.f,0.f}; o1[i] = (f32x4){0.f,0.f,0.f,0.f}; }
    f32x4 l0 = (f32x4){0.f,0.f,0.f,0.f};
    f32x4 l1 = (f32x4){0.f,0.f,0.f,0.f};

    for (int kt = 0; kt < nkt; ++kt) {
        int k0 = kt * 64;
        if (kt) stage(k0);   // guarded by the lgkmcnt(0)+barrier at loop end

        // K ready (own 4 oldest loads landed; barrier joins all waves).
        // Q-prologue loads are fully consumed before the loop, so exactly the
        // 8 staging loads are outstanding here: vmcnt(4) = wait for K.
        asm volatile("s_waitcnt vmcnt(4)" ::: "memory");
        __builtin_amdgcn_s_barrier();

        // causal geometry per (wave, qg): base = q-row-base - k0 (mult of 16)
        int base1 = (q0 - k0) + wave * 32 + 16;   // qg=1
        int base0 = base1 - 16;                   // qg=0
        int a1 = 0, a0 = 0, kcm1 = 0, kcm0 = 0;
        unsigned int Dlo1[4], Dhi1[4], Dlo0[4], Dhi0[4];
        if (base1 >= 0) {
            bool full1 = base1 >= 64, full0 = base0 >= 64;
            a1 = full1 ? 4 : ((base1 >> 4) + 1);             // active 16-key blocks
            a0 = (base0 < 0) ? 0 : (full0 ? 4 : ((base0 >> 4) + 1));
            kcm1 = (a1 + 1) >> 1;                            // active 32-key halves
            kcm0 = (a0 + 1) >> 1;

            // S^T[key][q] = K·Q^T, each ak fragment shared by both qg
            f32x4 s0[4], s1[4];
#pragma unroll
            for (int n = 0; n < 4; ++n) {
                s0[n] = (f32x4){0.f,0.f,0.f,0.f};
                s1[n] = (f32x4){0.f,0.f,0.f,0.f};
            }
            __builtin_amdgcn_s_setprio(1);
#pragma unroll
            for (int n = 0; n < 4; ++n) {
                if (n < a1) {      // a0 <= a1 always
#pragma unroll
                    for (int c = 0; c < 4; ++c) {
                        bf16x8 ak = *(const bf16x8*)&ks[(n * 16 + m16) * 128 +
                                                        (((c * 4 + g) ^ m16) * 8)];
                        s1[n] = __builtin_amdgcn_mfma_f32_16x16x32_bf16(ak, qf1[c], s1[n], 0, 0, 0);
                        if (n < a0)
                            s0[n] = __builtin_amdgcn_mfma_f32_16x16x32_bf16(ak, qf0[c], s0[n], 0, 0, 0);
                    }
                }
            }
            __builtin_amdgcn_s_setprio(0);

            // fixed-M softmax: p = exp2(score), causal mask post-exp; pack to
            // per-block dwords (inactive blocks packed as zeros).
#pragma unroll
            for (int n = 0; n < 4; ++n) {
                if (n < a1) {
                    float pr[4];
#pragma unroll
                    for (int r = 0; r < 4; ++r) {
                        float p = exp2f(s1[n][r]);
                        if (!full1) {
                            int key = n * 16 + g * 4 + r;
                            p = (key <= base1 + m16) ? p : 0.f;
                        }
                        pr[r] = p;
                    }
                    Dlo1[n] = f2bfu(pr[0]) | (f2bfu(pr[1]) << 16);
                    Dhi1[n] = f2bfu(pr[2]) | (f2bfu(pr[3]) << 16);
                } else { Dlo1[n] = 0u; Dhi1[n] = 0u; }
            }
            if (a0 > 0) {
#pragma unroll
                for (int n = 0; n < 4; ++n) {
                    if (n < a0) {
                        float pr[4];
#pragma unroll
                        for (int r = 0; r < 4; ++r) {
                            float p = exp2f(s0[n][r]);
                            if (!full0) {
                                int key = n * 16 + g * 4 + r;
                                p = (key <= base0 + m16) ? p : 0.f;
                            }
                            pr[r] = p;
                        }
                        Dlo0[n] = f2bfu(pr[0]) | (f2bfu(pr[1]) << 16);
                        Dhi0[n] = f2bfu(pr[2]) | (f2bfu(pr[3]) << 16);
                    } else { Dlo0[n] = 0u; Dhi0[n] = 0u; }
                }
            }
        }

        // V ready (all 8 own loads landed; barrier joins all waves).
        asm volatile("s_waitcnt vmcnt(0)" ::: "memory");
        __builtin_amdgcn_s_barrier();

        if (base1 >= 0) {
            // PV: each vb fragment shared by both qg; l via ones-MFMA
            __builtin_amdgcn_s_setprio(1);
#pragma unroll
            for (int kc = 0; kc < 2; ++kc) {
                if (kc < kcm1) {
                    bf16x8 pa1 = permpack(Dlo1, Dhi1, kc);
                    l1 = __builtin_amdgcn_mfma_f32_16x16x32_bf16(pa1, vones, l1, 0, 0, 0);
                    bool use0 = kc < kcm0;
                    bf16x8 pa0;
                    if (use0) {
                        pa0 = permpack(Dlo0, Dhi0, kc);
                        l0 = __builtin_amdgcn_mfma_f32_16x16x32_bf16(pa0, vones, l0, 0, 0, 0);
                    }
#pragma unroll
                    for (int ds = 0; ds < 8; ++ds) {
                        bf16x8 vb = *(const bf16x8*)&vs[(ds * 16 + m16) * 64 +
                                                        (((kc * 4 + g) ^ m8) * 8)];
                        o1[ds] = __builtin_amdgcn_mfma_f32_16x16x32_bf16(pa1, vb, o1[ds], 0, 0, 0);
                        if (use0)
                            o0[ds] = __builtin_amdgcn_mfma_f32_16x16x32_bf16(pa0, vb, o0[ds], 0, 0, 0);
                    }
                }
            }
            __builtin_amdgcn_s_setprio(0);
        }

        // all waves done reading ks/vs -> next iteration may overwrite
        asm volatile("s_waitcnt lgkmcnt(0)" ::: "memory");
        __builtin_amdgcn_s_barrier();
    }

    // epilogue: O /= l (l rows already C-layout), write fp32
#pragma unroll
    for (int r = 0; r < 4; ++r) {
        float inv0 = 1.f / l0[r];
        float* op0 = out + (((size_t)b * S_ + (q0 + wave * 32 + g * 4 + r)) * HQ_ + hq) * D_;
#pragma unroll
        for (int ds = 0; ds < 8; ++ds)
            op0[ds * 16 + m16] = o0[ds][r] * inv0;
        float inv1 = 1.f / l1[r];
        float* op1 = op0 + (size_t)16 * HQ_ * D_;
#pragma unroll
        for (int ds = 0; ds < 8; ++ds)
            op1[ds * 16 + m16] = o1[ds][r] * inv1;
    }
}

extern "C" void kernel_launch(void* const* d_in, const int* in_sizes, int n_in,
                              void* d_out, int out_size, void* d_ws, size_t ws_size,
                              hipStream_t stream) {
    const float* q = (const float*)d_in[0];
    const float* k = (const float*)d_in[1];
    const float* v = (const float*)d_in[2];
    float* out = (float*)d_out;

    unsigned short* kd  = (unsigned short*)d_ws;              // 8 MB
    unsigned short* vdT = kd + (size_t)NROW_ * D_;            // 8 MB

    prep<<<8704, 256, 0, stream>>>(k, v, kd, vdT);
    attn<<<dim3(64, 16), 256, 0, stream>>>(q, kd, vdT, out);
}

// Round 6
// 272.003 us; speedup vs baseline: 1.1739x; 1.1739x over previous
//
#include <hip/hip_runtime.h>
#include <cstdint>
#include <cstddef>

// Problem constants
#define B_    2
#define S_    2048
#define HQ_   32
#define HKV_  8
#define D_    128
#define QSCALE_ (0.08838834764831845f * 1.4426950408889634f)  // fold log2(e): softmax in base 2

#define NROW_ (B_*S_*HKV_)   // 32768 rows per tensor

typedef __bf16 bf16x8 __attribute__((ext_vector_type(8)));
typedef float  f32x4  __attribute__((ext_vector_type(4)));

__device__ __forceinline__ unsigned int f2bfu(float f) {
    __bf16 b = (__bf16)f;           // RTNE
    return (unsigned int)__builtin_bit_cast(unsigned short, b);
}

// async 16B/lane global->LDS; lds base must be wave-uniform (HW adds lane*16)
__device__ __forceinline__ void gl_lds16(const unsigned short* g, unsigned short* l) {
    __builtin_amdgcn_global_load_lds(
        (const __attribute__((address_space(1))) void*)g,
        (__attribute__((address_space(3))) void*)l, 16, 0, 0);
}

// Emulate reference quant_dequant_e4m3 exactly, branch/libcall-free.
__device__ __forceinline__ float qd_e4m3(float x) {
    float ax = fabsf(x);
    float xc = fminf(fmaxf(x, -448.f), 448.f);
    float axc = fmaxf(ax, 1e-12f);
    int e = (int)((__builtin_bit_cast(unsigned int, axc) >> 23) & 255u) - 127;
    e = min(max(e, -6), 8);
    float s1 = __builtin_bit_cast(float, (unsigned int)(130 - e) << 23); // 2^(3-e)
    float s2 = __builtin_bit_cast(float, (unsigned int)(124 + e) << 23); // 2^(e-3)
    float q = rintf(xc * s1) * s2;
    return ax == 0.f ? 0.f : q;
}

// fp4 e2m1 quant-dequant; searchsorted 'left' => ties at midpoints go DOWN
__device__ __forceinline__ float qd_fp4(float x, float scale) {
    float xn = x / scale;                    // IEEE div, matches numpy
    float a = fabsf(xn);
    float g;
    if      (a <= 0.25f) g = 0.f;
    else if (a <= 0.75f) g = 0.5f;
    else if (a <= 1.25f) g = 1.f;
    else if (a <= 1.75f) g = 1.5f;
    else if (a <= 2.5f)  g = 2.f;
    else if (a <= 3.5f)  g = 3.f;
    else if (a <= 5.f)   g = 4.f;
    else                 g = 6.f;
    return copysignf(g * scale, xn);
}

// Fused prep kernel (round-2/3/4-proven, passed).
// Blocks [0, 8192): quantize K -> bf16 dequantized [b][hkv][s][d].
// Blocks [8192, 8704): quantize V AND transpose to [b][hkv][d][s] in one pass.
__global__ __launch_bounds__(256) void prep(const float* __restrict__ k,
                                            const float* __restrict__ v,
                                            unsigned short* __restrict__ kd,
                                            unsigned short* __restrict__ vdT) {
    __shared__ alignas(16) unsigned short t[64][136];  // +8 pad (V path only)
    if (blockIdx.x < 8192) {
        // ---- K path: one wave per row, 2 elems/lane ----
        int gw = (blockIdx.x * 256 + threadIdx.x) >> 6;
        int lane = threadIdx.x & 63;
        int row = gw;
        int b   = row / (S_ * HKV_);
        int rem = row - b * (S_ * HKV_);
        int s   = rem >> 3;      // HKV = 8
        int h   = rem & 7;
        float2 x = *(const float2*)(k + (size_t)row * D_ + 2 * lane);
        float q0 = qd_e4m3(x.x);
        float q1 = qd_e4m3(x.y);
        float amax = fmaxf(fabsf(q0), fabsf(q1));
#pragma unroll
        for (int m = 1; m < 64; m <<= 1) amax = fmaxf(amax, __shfl_xor(amax, m, 64));
        float scale = fmaxf(amax / 6.0f, 1e-12f);
        float y0 = qd_fp4(q0, scale);
        float y1 = qd_fp4(q1, scale);
        size_t outOff = ((size_t)(b * HKV_ + h) * S_ + s) * D_ + 2 * lane;
        unsigned int pack = f2bfu(y0) | (f2bfu(y1) << 16);
        *(unsigned int*)(kd + outOff) = pack;
    } else {
        // ---- V path: quant (rows in pairs to pipeline shuffle-reduce chains)
        // then LDS transpose ----
        int bid = blockIdx.x - 8192;     // 0..511
        int bh = bid >> 5;               // b*HKV + h, 0..15
        int st = bid & 31;
        int s0 = st * 64;
        int b = bh >> 3;
        int h = bh & 7;
        int tid = threadIdx.x;
        int lane = tid & 63;
        int wave = tid >> 6;
#pragma unroll
        for (int i = 0; i < 8; ++i) {
            int rA = wave * 16 + 2 * i;
            const float* srcA = v + (((size_t)b * S_ + (s0 + rA)) * HKV_ + h) * D_ + 2 * lane;
            const float* srcB = srcA + (size_t)HKV_ * D_;   // next s
            float2 xA = *(const float2*)srcA;
            float2 xB = *(const float2*)srcB;
            float a0 = qd_e4m3(xA.x), a1 = qd_e4m3(xA.y);
            float c0 = qd_e4m3(xB.x), c1 = qd_e4m3(xB.y);
            float amA = fmaxf(fabsf(a0), fabsf(a1));
            float amB = fmaxf(fabsf(c0), fabsf(c1));
#pragma unroll
            for (int m = 1; m < 64; m <<= 1) {   // two independent chains interleave
                amA = fmaxf(amA, __shfl_xor(amA, m, 64));
                amB = fmaxf(amB, __shfl_xor(amB, m, 64));
            }
            float sA = fmaxf(amA / 6.0f, 1e-12f);
            float sB = fmaxf(amB / 6.0f, 1e-12f);
            unsigned int pA = f2bfu(qd_fp4(a0, sA)) | (f2bfu(qd_fp4(a1, sA)) << 16);
            unsigned int pB = f2bfu(qd_fp4(c0, sB)) | (f2bfu(qd_fp4(c1, sB)) << 16);
            *(unsigned int*)&t[rA][2 * lane]     = pA;
            *(unsigned int*)&t[rA + 1][2 * lane] = pB;
        }
        __syncthreads();
        int d = tid >> 1;
        unsigned short* dp = vdT + ((size_t)bh * D_ + d) * S_ + s0;
#pragma unroll
        for (int i = 0; i < 4; ++i) {
            int c = (tid & 1) + 2 * i;
            int so = c * 8;
            unsigned short tmp[8];
#pragma unroll
            for (int e = 0; e < 8; ++e) tmp[e] = t[so + e][d];
            *(uint4*)(dp + so) = *(uint4*)tmp;
        }
    }
}

// Kernel 2: causal GQA flash attention.
// SINGLE-VARIABLE EXPERIMENT vs round-1 (harness-passed, 120 VGPR, no spill):
// identical compute structure (2 q-groups/wave = 128q block, every K/V fragment
// read feeds 2 MFMAs; P via per-wave LDS; dbuf 80KB; launch_bounds(256,2)),
// but the two __syncthreads() per tile — which drained vmcnt(0) and serialized
// every prefetch — are replaced by the round-4-correctness-verified counted-
// vmcnt triple barrier, extended to the double buffer:
//   loop invariant: 8 loads (next tile) in flight at iter top.
//   issue stage(kt+1) -> 16 in flight -> vmcnt(12)+bar  (K of kt ready)
//   QK + softmax + P store                               (V still flying)
//   vmcnt(8)+lgkmcnt(0)+bar                              (V of kt ready)
//   PV -> lgkmcnt(0)+bar                                 (buf reads retired)
// Last iteration peels to vmcnt(4)/vmcnt(0). Counts are exact: Q-prep loads
// are consumed (compiler-waited) before the loop; in-loop no other VMEM.
// Round-4's spill disaster (launch_bounds(256,3) forced VGPR<=128 -> scratch)
// is avoided: (256,2) as round-1, which measured 120 VGPR for this layout.
__global__ __launch_bounds__(256, 2) void attn(const float* __restrict__ q,
                                               const unsigned short* __restrict__ kd,
                                               const unsigned short* __restrict__ vdT,
                                               float* __restrict__ out) {
    int bh = blockIdx.x;           // 0..63
    int yp = blockIdx.y;           // 0..7
    int b  = bh >> 5;
    int hq = bh & 31;
    int hkv = hq >> 2;             // GQA group of 4
    int tid  = threadIdx.x;
    int lane = tid & 63;
    int wave = tid >> 6;
    int m16  = lane & 15;
    int g    = lane >> 4;
    int m8   = m16 & 7;

    __shared__ alignas(16) unsigned short ks[2][64 * 128];   // K [key][d], swz ^(key&15) on 16B, dbuf
    __shared__ alignas(16) unsigned short vs[2][128 * 64];   // V^T [d][key], swz ^(d&7) on 16B, dbuf
    __shared__ alignas(16) unsigned short ps[4 * 2048];      // per-wave P: [wave][qg][q][key], swz ^q8

    const unsigned short* kbase = kd  + (size_t)(b * HKV_ + hkv) * S_ * D_;
    const unsigned short* vbase = vdT + (size_t)(b * HKV_ + hkv) * D_ * S_;

    bf16x8 vones;
#pragma unroll
    for (int j = 0; j < 8; ++j) vones[j] = (__bf16)1.0f;

    // stage one 64-key tile into buffer `buf`: K first (4 loads) then V (4) —
    // issue order is what the counted vmcnt waits rely on.
    auto stage = [&](int buf, int k0s) {
#pragma unroll
        for (int i = 0; i < 4; ++i) {
            int row = wave * 16 + i * 4 + (lane >> 4);
            int c = (lane & 15) ^ (row & 15);
            gl_lds16(kbase + (size_t)(k0s + row) * D_ + c * 8,
                     &ks[buf][wave * 2048 + i * 512]);
        }
#pragma unroll
        for (int i = 0; i < 4; ++i) {
            int d = wave * 32 + i * 8 + (lane >> 3);
            int c = (lane & 7) ^ (d & 7);
            gl_lds16(vbase + (size_t)d * S_ + k0s + c * 8,
                     &vs[buf][wave * 2048 + i * 512]);
        }
    };

    for (int phase = 0; phase < 2; ++phase) {
        int t  = phase ? yp : (15 - yp);   // q-tile of 128 rows
        int q0 = t * 128;
        int nkt = 2 * t + 2;               // 64-key tiles in causal range

        // Q fragments FIRST (their compiler-inserted waits then leave the
        // stage(0) prefetch below in flight), pre-scaled by SCALING*log2e
        bf16x8 qf0[4], qf1[4];
        {
            const float* qp0 = q + (((size_t)b * S_ + (q0 + wave * 32 + m16)) * HQ_ + hq) * D_;
            const float* qp1 = qp0 + (size_t)16 * HQ_ * D_;
#pragma unroll
            for (int c = 0; c < 4; ++c) {
                const float* a0 = qp0 + c * 32 + g * 8;
                const float* a1 = qp1 + c * 32 + g * 8;
                bf16x8 f0, f1;
#pragma unroll
                for (int j = 0; j < 8; ++j) {
                    f0[j] = (__bf16)(a0[j] * QSCALE_);
                    f1[j] = (__bf16)(a1[j] * QSCALE_);
                }
                qf0[c] = f0;
                qf1[c] = f1;
            }
        }

        f32x4 o0[8], o1[8];
#pragma unroll
        for (int i = 0; i < 8; ++i) { o0[i] = (f32x4){0.f,0.f,0.f,0.f}; o1[i] = (f32x4){0.f,0.f,0.f,0.f}; }
        f32x4 l0 = (f32x4){0.f,0.f,0.f,0.f};
        f32x4 l1 = (f32x4){0.f,0.f,0.f,0.f};

        // prologue prefetch: tile 0 into buf 0 (phase-0: fresh LDS; phase-1:
        // prior phase ended with lgkmcnt(0)+barrier, all readers retired)
        stage(0, 0);

        for (int kt = 0; kt < nkt; ++kt) {
            int cur = kt & 1;
            bool pre = (kt + 1 < nkt);     // block-uniform
            int k0 = kt * 64;
            if (pre) {
                stage(cur ^ 1, k0 + 64);   // 16 in flight
                asm volatile("s_waitcnt vmcnt(12)" ::: "memory");  // K(kt) ready
            } else {
                asm volatile("s_waitcnt vmcnt(4)" ::: "memory");   // K(kt) ready
            }
            __builtin_amdgcn_s_barrier();

            // causal geometry per (wave, qg): base = q-row-base - k0 (mult of 16)
            int base1 = (q0 - k0) + wave * 32 + 16;   // qg=1
            int base0 = base1 - 16;                   // qg=0
            int kcm1 = 0, kcm0 = 0;
            if (base1 >= 0) {
                bool full1 = base1 >= 64, full0 = base0 >= 64;
                int a1 = full1 ? 4 : ((base1 >> 4) + 1);            // active 16-key blocks
                int a0 = (base0 < 0) ? 0 : (full0 ? 4 : ((base0 >> 4) + 1));
                kcm1 = (a1 + 1) >> 1;                               // active 32-key halves
                kcm0 = (a0 + 1) >> 1;

                // S^T[key][q] = K·Q^T, each ak fragment shared by both qg
                f32x4 s0[4], s1[4];
#pragma unroll
                for (int n = 0; n < 4; ++n) {
                    s0[n] = (f32x4){0.f,0.f,0.f,0.f};
                    s1[n] = (f32x4){0.f,0.f,0.f,0.f};
                }
                __builtin_amdgcn_s_setprio(1);
#pragma unroll
                for (int n = 0; n < 4; ++n) {
                    if (n < a1) {      // a0 <= a1 always
#pragma unroll
                        for (int c = 0; c < 4; ++c) {
                            bf16x8 ak = *(const bf16x8*)&ks[cur][(n * 16 + m16) * 128 +
                                                                 (((c * 4 + g) ^ m16) * 8)];
                            s1[n] = __builtin_amdgcn_mfma_f32_16x16x32_bf16(ak, qf1[c], s1[n], 0, 0, 0);
                            if (n < a0)
                                s0[n] = __builtin_amdgcn_mfma_f32_16x16x32_bf16(ak, qf0[c], s0[n], 0, 0, 0);
                        }
                    }
                }
                __builtin_amdgcn_s_setprio(0);

                // fixed-M softmax + pack + wave-local P store (qg=1 then qg=0)
#pragma unroll
                for (int n = 0; n < 4; ++n) {
                    if (n < 2 * kcm1) {
                        unsigned int lo = 0, hi = 0;
                        if (n < a1) {
                            float pr[4];
#pragma unroll
                            for (int r = 0; r < 4; ++r) {
                                float p = exp2f(s1[n][r]);
                                if (!full1) {
                                    int key = n * 16 + g * 4 + r;
                                    p = (key <= base1 + m16) ? p : 0.f;
                                }
                                pr[r] = p;
                            }
                            lo = f2bfu(pr[0]) | (f2bfu(pr[1]) << 16);
                            hi = f2bfu(pr[2]) | (f2bfu(pr[3]) << 16);
                        }
                        int chunk = (n * 2 + (g >> 1)) ^ m8;
                        uint2 val; val.x = lo; val.y = hi;
                        *(uint2*)&ps[wave * 2048 + 1024 + m16 * 64 + chunk * 8 + (g & 1) * 4] = val;
                    }
                }
                if (a0 > 0) {
#pragma unroll
                    for (int n = 0; n < 4; ++n) {
                        if (n < 2 * kcm0) {
                            unsigned int lo = 0, hi = 0;
                            if (n < a0) {
                                float pr[4];
#pragma unroll
                                for (int r = 0; r < 4; ++r) {
                                    float p = exp2f(s0[n][r]);
                                    if (!full0) {
                                        int key = n * 16 + g * 4 + r;
                                        p = (key <= base0 + m16) ? p : 0.f;
                                    }
                                    pr[r] = p;
                                }
                                lo = f2bfu(pr[0]) | (f2bfu(pr[1]) << 16);
                                hi = f2bfu(pr[2]) | (f2bfu(pr[3]) << 16);
                            }
                            int chunk = (n * 2 + (g >> 1)) ^ m8;
                            uint2 val; val.x = lo; val.y = hi;
                            *(uint2*)&ps[wave * 2048 + m16 * 64 + chunk * 8 + (g & 1) * 4] = val;
                        }
                    }
                }
            }

            // V(kt) ready + own P stores visible (wave-local)
            if (pre) { asm volatile("s_waitcnt vmcnt(8) lgkmcnt(0)" ::: "memory"); }
            else     { asm volatile("s_waitcnt vmcnt(0) lgkmcnt(0)" ::: "memory"); }
            __builtin_amdgcn_s_barrier();

            if (base1 >= 0) {
                // PV: each vb fragment shared by both qg; l via ones-MFMA
                __builtin_amdgcn_s_setprio(1);
#pragma unroll
                for (int kc = 0; kc < 2; ++kc) {
                    if (kc < kcm1) {
                        bf16x8 pa1 = *(const bf16x8*)&ps[wave * 2048 + 1024 + m16 * 64 +
                                                         (((kc * 4 + g) ^ m8) * 8)];
                        l1 = __builtin_amdgcn_mfma_f32_16x16x32_bf16(pa1, vones, l1, 0, 0, 0);
                        bool use0 = kc < kcm0;
                        bf16x8 pa0;
                        if (use0) {
                            pa0 = *(const bf16x8*)&ps[wave * 2048 + m16 * 64 +
                                                      (((kc * 4 + g) ^ m8) * 8)];
                            l0 = __builtin_amdgcn_mfma_f32_16x16x32_bf16(pa0, vones, l0, 0, 0, 0);
                        }
#pragma unroll
                        for (int ds = 0; ds < 8; ++ds) {
                            bf16x8 vb = *(const bf16x8*)&vs[cur][(ds * 16 + m16) * 64 +
                                                                 (((kc * 4 + g) ^ m8) * 8)];
                            o1[ds] = __builtin_amdgcn_mfma_f32_16x16x32_bf16(pa1, vb, o1[ds], 0, 0, 0);
                            if (use0)
                                o0[ds] = __builtin_amdgcn_mfma_f32_16x16x32_bf16(pa0, vb, o0[ds], 0, 0, 0);
                        }
                    }
                }
                __builtin_amdgcn_s_setprio(0);
            }

            // all waves' ds_reads of buf `cur` and ps retired -> next iter may
            // overwrite buf cur (stage kt+2) and ps
            asm volatile("s_waitcnt lgkmcnt(0)" ::: "memory");
            __builtin_amdgcn_s_barrier();
        }

        // epilogue: O /= l (l rows already C-layout), write fp32
#pragma unroll
        for (int r = 0; r < 4; ++r) {
            float inv0 = 1.f / l0[r];
            float* op0 = out + (((size_t)b * S_ + (q0 + wave * 32 + g * 4 + r)) * HQ_ + hq) * D_;
#pragma unroll
            for (int ds = 0; ds < 8; ++ds)
                op0[ds * 16 + m16] = o0[ds][r] * inv0;
            float inv1 = 1.f / l1[r];
            float* op1 = op0 + (size_t)16 * HQ_ * D_;
#pragma unroll
            for (int ds = 0; ds < 8; ++ds)
                op1[ds * 16 + m16] = o1[ds][r] * inv1;
        }
    }
}

extern "C" void kernel_launch(void* const* d_in, const int* in_sizes, int n_in,
                              void* d_out, int out_size, void* d_ws, size_t ws_size,
                              hipStream_t stream) {
    const float* q = (const float*)d_in[0];
    const float* k = (const float*)d_in[1];
    const float* v = (const float*)d_in[2];
    float* out = (float*)d_out;

    unsigned short* kd  = (unsigned short*)d_ws;              // 8 MB
    unsigned short* vdT = kd + (size_t)NROW_ * D_;            // 8 MB

    prep<<<8704, 256, 0, stream>>>(k, v, kd, vdT);
    attn<<<dim3(64, 8), 256, 0, stream>>>(q, kd, vdT, out);
}

// Round 7
// 250.385 us; speedup vs baseline: 1.2752x; 1.0863x over previous
//
#include <hip/hip_runtime.h>
#include <cstdint>
#include <cstddef>

// Problem constants
#define B_    2
#define S_    2048
#define HQ_   32
#define HKV_  8
#define D_    128
#define QSCALE_ (0.08838834764831845f * 1.4426950408889634f)  // fold log2(e): softmax in base 2

#define NROW_ (B_*S_*HKV_)   // 32768 rows per tensor

typedef __bf16 bf16x8 __attribute__((ext_vector_type(8)));
typedef float  f32x4  __attribute__((ext_vector_type(4)));
typedef unsigned int u32x4 __attribute__((ext_vector_type(4)));

__device__ __forceinline__ unsigned int f2bfu(float f) {
    __bf16 b = (__bf16)f;           // RTNE
    return (unsigned int)__builtin_bit_cast(unsigned short, b);
}

// async 16B/lane global->LDS; lds base must be wave-uniform (HW adds lane*16)
__device__ __forceinline__ void gl_lds16(const unsigned short* g, unsigned short* l) {
    __builtin_amdgcn_global_load_lds(
        (const __attribute__((address_space(1))) void*)g,
        (__attribute__((address_space(3))) void*)l, 16, 0, 0);
}

// Emulate reference quant_dequant_e4m3 exactly, branch/libcall-free.
__device__ __forceinline__ float qd_e4m3(float x) {
    float ax = fabsf(x);
    float xc = fminf(fmaxf(x, -448.f), 448.f);
    float axc = fmaxf(ax, 1e-12f);
    int e = (int)((__builtin_bit_cast(unsigned int, axc) >> 23) & 255u) - 127;
    e = min(max(e, -6), 8);
    float s1 = __builtin_bit_cast(float, (unsigned int)(130 - e) << 23); // 2^(3-e)
    float s2 = __builtin_bit_cast(float, (unsigned int)(124 + e) << 23); // 2^(e-3)
    float q = rintf(xc * s1) * s2;
    return ax == 0.f ? 0.f : q;
}

// fp4 e2m1 quant-dequant; searchsorted 'left' => ties at midpoints go DOWN
__device__ __forceinline__ float qd_fp4(float x, float scale) {
    float xn = x / scale;                    // IEEE div, matches numpy
    float a = fabsf(xn);
    float g;
    if      (a <= 0.25f) g = 0.f;
    else if (a <= 0.75f) g = 0.5f;
    else if (a <= 1.25f) g = 1.f;
    else if (a <= 1.75f) g = 1.5f;
    else if (a <= 2.5f)  g = 2.f;
    else if (a <= 3.5f)  g = 3.f;
    else if (a <= 5.f)   g = 4.f;
    else                 g = 6.f;
    return copysignf(g * scale, xn);
}

// Fused prep kernel (round-2/3-proven, passed).
// Blocks [0, 8192): quantize K -> bf16 dequantized [b][hkv][s][d].
// Blocks [8192, 8704): quantize V AND transpose to [b][hkv][d][s] in one pass.
__global__ __launch_bounds__(256) void prep(const float* __restrict__ k,
                                            const float* __restrict__ v,
                                            unsigned short* __restrict__ kd,
                                            unsigned short* __restrict__ vdT) {
    __shared__ alignas(16) unsigned short t[64][136];  // +8 pad (V path only)
    if (blockIdx.x < 8192) {
        // ---- K path: one wave per row, 2 elems/lane ----
        int gw = (blockIdx.x * 256 + threadIdx.x) >> 6;
        int lane = threadIdx.x & 63;
        int row = gw;
        int b   = row / (S_ * HKV_);
        int rem = row - b * (S_ * HKV_);
        int s   = rem >> 3;      // HKV = 8
        int h   = rem & 7;
        float2 x = *(const float2*)(k + (size_t)row * D_ + 2 * lane);
        float q0 = qd_e4m3(x.x);
        float q1 = qd_e4m3(x.y);
        float amax = fmaxf(fabsf(q0), fabsf(q1));
#pragma unroll
        for (int m = 1; m < 64; m <<= 1) amax = fmaxf(amax, __shfl_xor(amax, m, 64));
        float scale = fmaxf(amax / 6.0f, 1e-12f);
        float y0 = qd_fp4(q0, scale);
        float y1 = qd_fp4(q1, scale);
        size_t outOff = ((size_t)(b * HKV_ + h) * S_ + s) * D_ + 2 * lane;
        unsigned int pack = f2bfu(y0) | (f2bfu(y1) << 16);
        *(unsigned int*)(kd + outOff) = pack;
    } else {
        // ---- V path: quant (rows in pairs to pipeline shuffle-reduce chains)
        // then LDS transpose ----
        int bid = blockIdx.x - 8192;     // 0..511
        int bh = bid >> 5;               // b*HKV + h, 0..15
        int st = bid & 31;
        int s0 = st * 64;
        int b = bh >> 3;
        int h = bh & 7;
        int tid = threadIdx.x;
        int lane = tid & 63;
        int wave = tid >> 6;
#pragma unroll
        for (int i = 0; i < 8; ++i) {
            int rA = wave * 16 + 2 * i;
            const float* srcA = v + (((size_t)b * S_ + (s0 + rA)) * HKV_ + h) * D_ + 2 * lane;
            const float* srcB = srcA + (size_t)HKV_ * D_;   // next s
            float2 xA = *(const float2*)srcA;
            float2 xB = *(const float2*)srcB;
            float a0 = qd_e4m3(xA.x), a1 = qd_e4m3(xA.y);
            float c0 = qd_e4m3(xB.x), c1 = qd_e4m3(xB.y);
            float amA = fmaxf(fabsf(a0), fabsf(a1));
            float amB = fmaxf(fabsf(c0), fabsf(c1));
#pragma unroll
            for (int m = 1; m < 64; m <<= 1) {   // two independent chains interleave
                amA = fmaxf(amA, __shfl_xor(amA, m, 64));
                amB = fmaxf(amB, __shfl_xor(amB, m, 64));
            }
            float sA = fmaxf(amA / 6.0f, 1e-12f);
            float sB = fmaxf(amB / 6.0f, 1e-12f);
            unsigned int pA = f2bfu(qd_fp4(a0, sA)) | (f2bfu(qd_fp4(a1, sA)) << 16);
            unsigned int pB = f2bfu(qd_fp4(c0, sB)) | (f2bfu(qd_fp4(c1, sB)) << 16);
            *(unsigned int*)&t[rA][2 * lane]     = pA;
            *(unsigned int*)&t[rA + 1][2 * lane] = pB;
        }
        __syncthreads();
        int d = tid >> 1;
        unsigned short* dp = vdT + ((size_t)bh * D_ + d) * S_ + s0;
#pragma unroll
        for (int i = 0; i < 4; ++i) {
            int c = (tid & 1) + 2 * i;
            int so = c * 8;
            unsigned short tmp[8];
#pragma unroll
            for (int e = 0; e < 8; ++e) tmp[e] = t[so + e][d];
            *(uint4*)(dp + so) = *(uint4*)tmp;
        }
    }
}

// P redistribution C-layout -> PV A-fragment, in registers (round-3-verified
// on HW): 2x permlane32_swap + 2x permlane16_swap per 32-key chunk.
__device__ __forceinline__ bf16x8 permpack(const unsigned int* Dlo,
                                           const unsigned int* Dhi, int kc) {
    auto p0 = __builtin_amdgcn_permlane32_swap(Dlo[2 * kc], Dlo[2 * kc + 1], false, false);
    auto p1 = __builtin_amdgcn_permlane32_swap(Dhi[2 * kc], Dhi[2 * kc + 1], false, false);
    auto r0 = __builtin_amdgcn_permlane16_swap(p0[0], p0[1], false, false);
    auto r1 = __builtin_amdgcn_permlane16_swap(p1[0], p1[1], false, false);
    u32x4 pau = (u32x4){r0[0], r1[0], r0[1], r1[1]};  // A-dwords 0..3
    return __builtin_bit_cast(bf16x8, pau);
}

// Kernel 2: causal GQA flash attention.
// THEORY (r0..r5 evidence): per-CU the pipes SUM (LDS ~1150 + VALU ~1200 +
// MFMA ~550 cy/unit ~= measured 2675 cy/unit) because every wave runs the same
// serial phase chain QK(MFMA)->softmax(VALU)->PV(MFMA) and barriers keep waves
// phase-correlated. Occupancy/staging/traffic changes never touched this ->
// all neutral. FIX: software-pipeline PV one k-tile behind, so softmax(kt)
// VALU and PV(kt-1) MFMA are co-resident, dependency-free, source-interleaved
// -> VALU and MFMA pipes overlap within every wave.
//   Base: r3-proven kernel (P in regs via permlane, 0 bank conflicts).
//   V double-buffered (48KB LDS -> 3 blk/CU); in-loop PV always a FULL tile
//   (diag tile's PV moves to epilogue -> uniform hot loop); counted vmcnt:
//   per-wave in-flight at iter top = {V(kt-1),K(kt),V(kt)} = 12 loads ->
//   vmcnt(4) retires exactly K(kt)+V(kt-1), never drains the newest prefetch.
__global__ __launch_bounds__(256) void attn(const float* __restrict__ q,
                                            const unsigned short* __restrict__ kd,
                                            const unsigned short* __restrict__ vdT,
                                            float* __restrict__ out) {
    int bh = blockIdx.x;           // 0..63
    int qt = 31 - blockIdx.y;      // heaviest q-tiles dispatched first
    int b  = bh >> 5;
    int hq = bh & 31;
    int hkv = hq >> 2;             // GQA group of 4
    int tid  = threadIdx.x;
    int lane = tid & 63;
    int wave = tid >> 6;
    int m16  = lane & 15;
    int g    = lane >> 4;
    int m8   = m16 & 7;

    __shared__ alignas(16) unsigned short ks[64 * 128];      // K [key][d], swz ^(key&15) on 16B
    __shared__ alignas(16) unsigned short vs[2][128 * 64];   // V^T [d][key], swz ^(d&7), dbuf

    const unsigned short* kbase = kd  + (size_t)(b * HKV_ + hkv) * S_ * D_;
    const unsigned short* vbase = vdT + (size_t)(b * HKV_ + hkv) * D_ * S_;

    bf16x8 vones;
#pragma unroll
    for (int j = 0; j < 8; ++j) vones[j] = (__bf16)1.0f;

    // staging: K first (4 loads) then V (4 loads) — counted vmcnt relies on order
    auto stageK = [&](int k0s) {
#pragma unroll
        for (int i = 0; i < 4; ++i) {
            int row = wave * 16 + i * 4 + (lane >> 4);
            int c = (lane & 15) ^ (row & 15);
            gl_lds16(kbase + (size_t)(k0s + row) * D_ + c * 8,
                     &ks[wave * 2048 + i * 512]);
        }
    };
    auto stageV = [&](int buf, int k0s) {
#pragma unroll
        for (int i = 0; i < 4; ++i) {
            int d = wave * 32 + i * 8 + (lane >> 3);
            int c = (lane & 7) ^ (d & 7);
            gl_lds16(vbase + (size_t)d * S_ + k0s + c * 8,
                     &vs[buf][wave * 2048 + i * 512]);
        }
    };

    int q0 = qt * 64;
    int qrowBase = q0 + wave * 16;

    // prologue prefetch of tile 0 (the Q-prep's compiler waits will drain it
    // once — acceptable, happens once per block, not per tile)
    stageK(0);
    stageV(0, 0);

    // Q fragments pre-scaled by SCALING*log2e
    bf16x8 qf[4];
    const float* qp = q + (((size_t)b * S_ + (qrowBase + m16)) * HQ_ + hq) * D_;
#pragma unroll
    for (int c = 0; c < 4; ++c) {
        const float* p0 = qp + c * 32 + g * 8;
        bf16x8 f;
#pragma unroll
        for (int j = 0; j < 8; ++j) f[j] = (__bf16)(p0[j] * QSCALE_);
        qf[c] = f;
    }

    f32x4 o[8];
#pragma unroll
    for (int i = 0; i < 8; ++i) o[i] = (f32x4){0.f, 0.f, 0.f, 0.f};
    f32x4 o9 = (f32x4){0.f, 0.f, 0.f, 0.f};   // l accumulator (P · ones)
    bf16x8 paPrev0, paPrev1;                   // P(kt-1) A-fragments

    int qloc = wave * 16 + m16;   // query - k0 on the diagonal tile

    for (int kt = 0; kt <= qt; ++kt) {
        // K(kt) ready; V(kt-1) ready (needed by PV below); V(kt) may fly.
        asm volatile("s_waitcnt vmcnt(4)" ::: "memory");
        __builtin_amdgcn_s_barrier();

        bool diag = (kt == qt);

        // [A] S^T[key][q] = K·Q^T : A = K rows, B = Q rows
        f32x4 sacc[4];
#pragma unroll
        for (int n = 0; n < 4; ++n) sacc[n] = (f32x4){0.f, 0.f, 0.f, 0.f};
        __builtin_amdgcn_s_setprio(1);
#pragma unroll
        for (int n = 0; n < 4; ++n) {
            if (!diag || n <= wave) {
#pragma unroll
                for (int c = 0; c < 4; ++c) {
                    bf16x8 ak = *(const bf16x8*)&ks[(n * 16 + m16) * 128 +
                                                    (((c * 4 + g) ^ m16) * 8)];
                    sacc[n] = __builtin_amdgcn_mfma_f32_16x16x32_bf16(ak, qf[c], sacc[n], 0, 0, 0);
                }
            }
        }
        __builtin_amdgcn_s_setprio(0);

        // all waves done reading ks -> safe to restage K
        asm volatile("s_waitcnt lgkmcnt(0)" ::: "memory");
        __builtin_amdgcn_s_barrier();
        if (kt < qt) stageK((kt + 1) * 64);

        // [C'] softmax(kt) (VALU) source-interleaved with PV(kt-1) (MFMA).
        // Streams are independent: softmax uses sacc/Dl/Dh; PV uses paPrev +
        // vs[(kt-1)&1]. In-loop PV tiles are always full (diag PV in epilogue).
        unsigned int Dlo[4], Dhi[4];
#pragma unroll
        for (int n = 0; n < 2; ++n) {
            if (!diag || n <= wave) {
                float pr[4];
#pragma unroll
                for (int r = 0; r < 4; ++r) {
                    float p = exp2f(sacc[n][r]);
                    if (diag) {
                        int key = n * 16 + g * 4 + r;
                        p = (key <= qloc) ? p : 0.f;
                    }
                    pr[r] = p;
                }
                Dlo[n] = f2bfu(pr[0]) | (f2bfu(pr[1]) << 16);
                Dhi[n] = f2bfu(pr[2]) | (f2bfu(pr[3]) << 16);
            } else { Dlo[n] = 0u; Dhi[n] = 0u; }
        }
        bf16x8 paNew0 = permpack(Dlo, Dhi, 0);
        if (kt > 0) {
            int pb = (kt - 1) & 1;
            o9 = __builtin_amdgcn_mfma_f32_16x16x32_bf16(paPrev0, vones, o9, 0, 0, 0);
#pragma unroll
            for (int ds = 0; ds < 8; ++ds) {
                bf16x8 vb = *(const bf16x8*)&vs[pb][(ds * 16 + m16) * 64 + ((g ^ m8) * 8)];
                o[ds] = __builtin_amdgcn_mfma_f32_16x16x32_bf16(paPrev0, vb, o[ds], 0, 0, 0);
            }
        }
#pragma unroll
        for (int n = 2; n < 4; ++n) {
            if (!diag || n <= wave) {
                float pr[4];
#pragma unroll
                for (int r = 0; r < 4; ++r) {
                    float p = exp2f(sacc[n][r]);
                    if (diag) {
                        int key = n * 16 + g * 4 + r;
                        p = (key <= qloc) ? p : 0.f;
                    }
                    pr[r] = p;
                }
                Dlo[n] = f2bfu(pr[0]) | (f2bfu(pr[1]) << 16);
                Dhi[n] = f2bfu(pr[2]) | (f2bfu(pr[3]) << 16);
            } else { Dlo[n] = 0u; Dhi[n] = 0u; }
        }
        bf16x8 paNew1 = permpack(Dlo, Dhi, 1);
        if (kt > 0) {
            int pb = (kt - 1) & 1;
            o9 = __builtin_amdgcn_mfma_f32_16x16x32_bf16(paPrev1, vones, o9, 0, 0, 0);
#pragma unroll
            for (int ds = 0; ds < 8; ++ds) {
                bf16x8 vb = *(const bf16x8*)&vs[pb][(ds * 16 + m16) * 64 + (((4 + g) ^ m8) * 8)];
                o[ds] = __builtin_amdgcn_mfma_f32_16x16x32_bf16(paPrev1, vb, o[ds], 0, 0, 0);
            }
        }

        // all waves done reading vs[(kt-1)&1] -> safe to restage it as V(kt+1)
        asm volatile("s_waitcnt lgkmcnt(0)" ::: "memory");
        __builtin_amdgcn_s_barrier();
        if (kt < qt) stageV((kt + 1) & 1, (kt + 1) * 64);

        paPrev0 = paNew0;
        paPrev1 = paNew1;
    }

    // epilogue PV(qt): diagonal tile, reduced key range
    asm volatile("s_waitcnt vmcnt(0)" ::: "memory");   // V(qt) landed
    __builtin_amdgcn_s_barrier();
    {
        int pb = qt & 1;
        int kcmax = (wave >> 1) + 1;
        // kc = 0
        o9 = __builtin_amdgcn_mfma_f32_16x16x32_bf16(paPrev0, vones, o9, 0, 0, 0);
#pragma unroll
        for (int ds = 0; ds < 8; ++ds) {
            bf16x8 vb = *(const bf16x8*)&vs[pb][(ds * 16 + m16) * 64 + ((g ^ m8) * 8)];
            o[ds] = __builtin_amdgcn_mfma_f32_16x16x32_bf16(paPrev0, vb, o[ds], 0, 0, 0);
        }
        // kc = 1 (only waves 2,3 have keys there)
        if (kcmax > 1) {
            o9 = __builtin_amdgcn_mfma_f32_16x16x32_bf16(paPrev1, vones, o9, 0, 0, 0);
#pragma unroll
            for (int ds = 0; ds < 8; ++ds) {
                bf16x8 vb = *(const bf16x8*)&vs[pb][(ds * 16 + m16) * 64 + (((4 + g) ^ m8) * 8)];
                o[ds] = __builtin_amdgcn_mfma_f32_16x16x32_bf16(paPrev1, vb, o[ds], 0, 0, 0);
            }
        }
    }

    // epilogue: O /= l (o9 rows are already C-layout), write fp32
#pragma unroll
    for (int r = 0; r < 4; ++r) {
        float inv = 1.f / o9[r];
        float* op = out + (((size_t)b * S_ + (qrowBase + g * 4 + r)) * HQ_ + hq) * D_;
#pragma unroll
        for (int ds = 0; ds < 8; ++ds)
            op[ds * 16 + m16] = o[ds][r] * inv;
    }
}

extern "C" void kernel_launch(void* const* d_in, const int* in_sizes, int n_in,
                              void* d_out, int out_size, void* d_ws, size_t ws_size,
                              hipStream_t stream) {
    const float* q = (const float*)d_in[0];
    const float* k = (const float*)d_in[1];
    const float* v = (const float*)d_in[2];
    float* out = (float*)d_out;

    unsigned short* kd  = (unsigned short*)d_ws;              // 8 MB
    unsigned short* vdT = kd + (size_t)NROW_ * D_;            // 8 MB

    prep<<<8704, 256, 0, stream>>>(k, v, kd, vdT);
    attn<<<dim3(64, 32), 256, 0, stream>>>(q, kd, vdT, out);
}